// Round 9
// baseline (125.562 us; speedup 1.0000x reference)
//
#include <hip/hip_runtime.h>

#define DIMX 100
#define BATCH 131072

typedef __bf16 bf16x8 __attribute__((ext_vector_type(8)));
typedef float  f32x4  __attribute__((ext_vector_type(4)));

// ---- kernel 1: convert A (100x100 fp32) to zero-padded bf16 [112][128] in ws ----
__global__ void conv_A(const float* __restrict__ A, __bf16* __restrict__ ws) {
    int i = blockIdx.x * 256 + threadIdx.x;          // 112*128 = 14336
    if (i < 112 * 128) {
        int j = i >> 7, k = i & 127;
        float v = (j < DIMX && k < DIMX) ? A[j * DIMX + k] : 0.0f;
        ws[i] = (__bf16)v;
    }
}

// ---- main kernel: NO LDS, no barriers. Operand-swapped MFMA:
//   D = mfma(A_matrix_frag, s_frag)  =>  D[row=j, col=batch_row]
// so acc[q] belongs to (batch_row = r0+fr, j = n*16 + h*4 + q): each lane owns
// 4 CONSECUTIVE output columns of its own row -> fp32 float4 epilogue + stores.
// R7 lesson: no big staged register arrays (spills). R5: no min-wave clamp.
template <bool USE_WS>
__global__ __launch_bounds__(128) void ca_main(
    const float* __restrict__ state, const float* __restrict__ Amat,
    const __bf16* __restrict__ Bws, const float* __restrict__ target,
    float* __restrict__ out)
{
    const int tid = threadIdx.x;
    const int wave = tid >> 6, lane = tid & 63;
    const int fr = lane & 15, h = lane >> 4;
    const long r0 = (long)blockIdx.x * 32 + wave * 16;   // wave's first row
    const long row = r0 + fr;                            // this lane's batch row
    const float* rp = state + row * 400;
    float* op = out + row * 400;

    // ---- s-fragments (B-operand): lane fr = batch row, k = kt*32 + h*8 + e ----
    bf16x8 sfrag[4];
#pragma unroll
    for (int kt = 0; kt < 4; ++kt) {
        int k0 = kt * 32 + h * 8;
        bf16x8 f = {};
        if (k0 < DIMX) {
            f32x4 xa = *reinterpret_cast<const f32x4*>(rp + k0);
            f32x4 xb = *reinterpret_cast<const f32x4*>(rp + k0 + 4);
#pragma unroll
            for (int e = 0; e < 8; ++e) {
                float x = (e < 4) ? xa[e] : xb[e - 4];
                float x2 = x * x;
                float s = x2 * __builtin_amdgcn_rcpf(1.0f + x2);
                f[e] = (k0 + e < DIMX) ? (__bf16)s : (__bf16)0.0f;
            }
        }
        sfrag[kt] = f;
    }

    // ---- zeros half: cols 200..399 for the wave's 16 rows (fire-and-forget) ----
#pragma unroll
    for (int it = 0; it < 13; ++it) {
        int i = lane + it * 64;                          // 16 rows x 50 quads = 800
        if (i < 800) {
            int r = i / 50, c4 = i - r * 50;
            __builtin_nontemporal_store(f32x4{0.f, 0.f, 0.f, 0.f},
                reinterpret_cast<f32x4*>(&out[(r0 + r) * 400 + 200 + c4 * 4]));
        }
    }

    // ---- per n-tile: MFMA (swapped) + fused fp32 epilogue ----
#pragma unroll
    for (int n = 0; n < 7; ++n) {
        f32x4 acc = {0.f, 0.f, 0.f, 0.f};
#pragma unroll
        for (int kt = 0; kt < 4; ++kt) {
            bf16x8 af;                                   // A-operand = A-matrix row j = n*16+fr
            if constexpr (USE_WS) {
                af = *reinterpret_cast<const bf16x8*>(
                    Bws + (n * 16 + fr) * 128 + kt * 32 + h * 8);
            } else {
                int jj = n * 16 + fr;
#pragma unroll
                for (int e = 0; e < 8; ++e) {
                    int k = kt * 32 + h * 8 + e;
                    float v = (jj < DIMX && k < DIMX) ? Amat[jj * DIMX + k] : 0.0f;
                    af[e] = (__bf16)v;
                }
            }
            acc = __builtin_amdgcn_mfma_f32_16x16x32_bf16(af, sfrag[kt], acc, 0, 0, 0);
        }
        int j0 = n * 16 + h * 4;                         // lane's 4 consecutive cols
        if (j0 < DIMX) {                                 // j0 <= 96 -> quad in-bounds
            f32x4 x = *reinterpret_cast<const f32x4*>(rp + j0);
            f32x4 e = *reinterpret_cast<const f32x4*>(rp + DIMX + j0);
            f32x4 w = *reinterpret_cast<const f32x4*>(rp + 3 * DIMX + j0);
            f32x4 t = *reinterpret_cast<const f32x4*>(target + j0);
            f32x4 dx, ndx;
#pragma unroll
            for (int q = 0; q < 4; ++q) {
                float u  = w[q] * (x[q] + e[q] - t[q]);
                float x2 = x[q] * x[q];
                float s  = x2 * __builtin_amdgcn_rcpf(1.0f + x2);
                float v  = acc[q] + fmaf(u, s, -x[q]);
                dx[q] = v; ndx[q] = -v;
            }
            __builtin_nontemporal_store(dx,  reinterpret_cast<f32x4*>(op + j0));
            __builtin_nontemporal_store(ndx, reinterpret_cast<f32x4*>(op + DIMX + j0));
        }
    }
}

extern "C" void kernel_launch(void* const* d_in, const int* in_sizes, int n_in,
                              void* d_out, int out_size, void* d_ws, size_t ws_size,
                              hipStream_t stream) {
    const float* state  = (const float*)d_in[0];
    const float* Amat   = (const float*)d_in[1];
    const float* target = (const float*)d_in[2];
    float* out = (float*)d_out;
    (void)in_sizes; (void)n_in; (void)out_size;

    if (ws_size >= (size_t)(112 * 128 * sizeof(__bf16))) {
        conv_A<<<dim3(56), dim3(256), 0, stream>>>(Amat, (__bf16*)d_ws);
        ca_main<true><<<dim3(BATCH / 32), dim3(128), 0, stream>>>(
            state, Amat, (const __bf16*)d_ws, target, out);
    } else {
        ca_main<false><<<dim3(BATCH / 32), dim3(128), 0, stream>>>(
            state, Amat, nullptr, target, out);
    }
}

// Round 10
// 71.603 us; speedup vs baseline: 1.7536x; 1.7536x over previous
//
#include <hip/hip_runtime.h>

#define DIMX 100
#define BATCH 131072
#define DXW 104           // f32 stride for dx tile: 416 B, 16B-aligned

typedef __bf16 bf16x8 __attribute__((ext_vector_type(8)));
typedef float  f32x4  __attribute__((ext_vector_type(4)));

// ---- kernel 1: convert A (100x100 fp32) to zero-padded bf16 [112][128] in ws ----
__global__ void conv_A(const float* __restrict__ A, __bf16* __restrict__ ws) {
    int i = blockIdx.x * 256 + threadIdx.x;          // 112*128 = 14336
    if (i < 112 * 128) {
        int j = i >> 7, k = i & 127;
        float v = (j < DIMX && k < DIMX) ? A[j * DIMX + k] : 0.0f;
        ws[i] = (__bf16)v;
    }
}

// ---- main kernel: swapped MFMA (lane owns 4 consecutive cols of its row),
// base fused fp32 in epilogue, dx staged in small fp32 LDS tile, then one
// fully-contiguous 64B-aligned NT sweep writes [dx,-dx,0,0].
// R9 lesson: direct fragment-layout global stores are line-misaligned for the
// -dx half (+40MB write inflation) — always store via the full-row sweep.
// R7: no big staged register arrays (spills). R5: no min-wave clamp.
template <bool USE_WS>
__global__ __launch_bounds__(128) void ca_main(
    const float* __restrict__ state, const float* __restrict__ Amat,
    const __bf16* __restrict__ Bws, const float* __restrict__ target,
    float* __restrict__ out)
{
    __shared__ __align__(16) float dxbuf[2][16 * DXW];   // 13312 B/block

    const int tid = threadIdx.x;
    const int wave = tid >> 6, lane = tid & 63;
    float* __restrict__ wbuf = dxbuf[wave];
    const int fr = lane & 15, h = lane >> 4;
    const long r0 = (long)blockIdx.x * 32 + wave * 16;   // wave's first row
    const float* rp = state + (r0 + fr) * 400;           // this lane's batch row

    // ---- s-fragments (B-operand): lane fr = batch row, k = kt*32 + h*8 + e ----
    bf16x8 sfrag[4];
#pragma unroll
    for (int kt = 0; kt < 4; ++kt) {
        int k0 = kt * 32 + h * 8;
        bf16x8 f = {};
        if (k0 < DIMX) {
            f32x4 xa = *reinterpret_cast<const f32x4*>(rp + k0);
            f32x4 xb = *reinterpret_cast<const f32x4*>(rp + k0 + 4);
#pragma unroll
            for (int e = 0; e < 8; ++e) {
                float x = (e < 4) ? xa[e] : xb[e - 4];
                float x2 = x * x;
                float s = x2 * __builtin_amdgcn_rcpf(1.0f + x2);
                f[e] = (k0 + e < DIMX) ? (__bf16)s : (__bf16)0.0f;
            }
        }
        sfrag[kt] = f;
    }

    // ---- per n-tile: MFMA (swapped) + fused fp32 base epilogue -> LDS dx ----
#pragma unroll
    for (int n = 0; n < 7; ++n) {
        f32x4 acc = {0.f, 0.f, 0.f, 0.f};
#pragma unroll
        for (int kt = 0; kt < 4; ++kt) {
            bf16x8 af;                                   // A-operand = A row j = n*16+fr
            if constexpr (USE_WS) {
                af = *reinterpret_cast<const bf16x8*>(
                    Bws + (n * 16 + fr) * 128 + kt * 32 + h * 8);
            } else {
                int jj = n * 16 + fr;
#pragma unroll
                for (int e = 0; e < 8; ++e) {
                    int k = kt * 32 + h * 8 + e;
                    float v = (jj < DIMX && k < DIMX) ? Amat[jj * DIMX + k] : 0.0f;
                    af[e] = (__bf16)v;
                }
            }
            acc = __builtin_amdgcn_mfma_f32_16x16x32_bf16(af, sfrag[kt], acc, 0, 0, 0);
        }
        int j0 = n * 16 + h * 4;                         // lane's 4 consecutive cols
        if (j0 < DIMX) {                                 // j0 <= 96 -> quad in-bounds
            f32x4 x = *reinterpret_cast<const f32x4*>(rp + j0);
            f32x4 e = *reinterpret_cast<const f32x4*>(rp + DIMX + j0);
            f32x4 w = *reinterpret_cast<const f32x4*>(rp + 3 * DIMX + j0);
            f32x4 t = *reinterpret_cast<const f32x4*>(target + j0);
            f32x4 dx;
#pragma unroll
            for (int q = 0; q < 4; ++q) {
                float u  = w[q] * (x[q] + e[q] - t[q]);
                float x2 = x[q] * x[q];
                float s  = x2 * __builtin_amdgcn_rcpf(1.0f + x2);
                dx[q] = acc[q] + fmaf(u, s, -x[q]);
            }
            *reinterpret_cast<f32x4*>(&wbuf[fr * DXW + j0]) = dx;
        }
    }

    // ---- final sweep: contiguous 64B-aligned NT float4 writes [dx,-dx,0,0] ----
#pragma unroll
    for (int it = 0; it < 25; ++it) {
        int i = lane + it * 64;                          // 16 rows x 100 quads
        int row = i / 100, c4 = i - row * 100;
        f32x4 v;
        if (c4 < 25) {
            v = *reinterpret_cast<const f32x4*>(&wbuf[row * DXW + c4 * 4]);
        } else if (c4 < 50) {
            f32x4 d = *reinterpret_cast<const f32x4*>(&wbuf[row * DXW + (c4 - 25) * 4]);
            v = f32x4{-d[0], -d[1], -d[2], -d[3]};
        } else {
            v = f32x4{0.f, 0.f, 0.f, 0.f};
        }
        __builtin_nontemporal_store(v,
            reinterpret_cast<f32x4*>(&out[(r0 + row) * 400 + c4 * 4]));
    }
}

extern "C" void kernel_launch(void* const* d_in, const int* in_sizes, int n_in,
                              void* d_out, int out_size, void* d_ws, size_t ws_size,
                              hipStream_t stream) {
    const float* state  = (const float*)d_in[0];
    const float* Amat   = (const float*)d_in[1];
    const float* target = (const float*)d_in[2];
    float* out = (float*)d_out;
    (void)in_sizes; (void)n_in; (void)out_size;

    if (ws_size >= (size_t)(112 * 128 * sizeof(__bf16))) {
        conv_A<<<dim3(56), dim3(256), 0, stream>>>(Amat, (__bf16*)d_ws);
        ca_main<true><<<dim3(BATCH / 32), dim3(128), 0, stream>>>(
            state, Amat, (const __bf16*)d_ws, target, out);
    } else {
        ca_main<false><<<dim3(BATCH / 32), dim3(128), 0, stream>>>(
            state, Amat, nullptr, target, out);
    }
}